// Round 1
// baseline (301.506 us; speedup 1.0000x reference)
//
#include <hip/hip_runtime.h>
#include <math.h>

// Shift_11261404250938: per-image shift(trunc(±10%)) + zero-fill, standardize,
// min-max normalize. Standardization cancels in the min-max step, so
// out = (shifted - min) / (max - min).
//
// R2 -> R3: the fused one-block-per-image kernel capped the grid at 256 blocks
// (1 block/CU, 16 waves/CU, 37% occupancy) and serialized read-phase /
// reduction / write-phase behind a block-wide barrier -> only 2.6 TB/s.
// Split into two full-occupancy streaming kernels linked via workspace:
//   minmax_k: 8 blocks/image x 256 thr, partial (min,max) -> d_ws.
//   norm_k:   8 blocks/image x 256 thr, folds the 8 partials (uniform L2-hit
//             loads), then the verified gather+normalize+store. Its x re-reads
//             hit the 256 MB Infinity Cache (input = 154 MB, just streamed).
// Grid = 2048 blocks of 256 -> 32 waves/CU.

constexpr int kC = 3, kH = 224, kW = 224;
constexpr int kCHW = kC * kH * kW;   // 150528
constexpr int kROWS = kC * kH;       // 672
constexpr int kQPR  = kW / 4;        // 56 quads per row
constexpr int kNQ   = kROWS * kQPR;  // 37632 quads per image
constexpr int TB    = 256;           // threads per block
constexpr int PARTS = 8;             // blocks per image (both kernels)

__device__ __forceinline__ void shifts_for(const float* __restrict__ sfy,
                                           const float* __restrict__ sfx,
                                           int img, int& sy, int& sx)
{
    // Replicate reference fp32 order: ((f*2-1)*0.1f)*size, trunc toward zero.
    float ty = sfy[img] * 2.0f - 1.0f; ty *= 0.1f; ty *= (float)kH;
    sy = (int)truncf(ty);
    float tx = sfx[img] * 2.0f - 1.0f; tx *= 0.1f; tx *= (float)kW;
    sx = (int)truncf(tx);
}

// ---------------- Kernel 1: per-slice min/max partials ----------------
__global__ __launch_bounds__(TB) void minmax_k(
    const float* __restrict__ x, const float* __restrict__ sfy,
    const float* __restrict__ sfx, float2* __restrict__ ws)
{
    const int img  = blockIdx.x / PARTS;
    const int part = blockIdx.x - img * PARTS;
    const float* __restrict__ xb = x + (size_t)img * kCHW;

    int sy, sx; shifts_for(sfy, sfx, img, sy, sx);

    // Valid input sub-rectangle (rows/cols of x that survive the shift).
    const int rlo = sy > 0 ? sy : 0;
    const int rhi = kH + (sy < 0 ? sy : 0);
    const int clo = sx > 0 ? sx : 0;
    const int chi = kW + (sx < 0 ? sx : 0);

    float vmin = INFINITY, vmax = -INFINITY;

    // Aligned float4 streaming min/max; invalid (shifted-out) elements -> 0,
    // which is exactly what the zero-fill contributes to min/max.
    for (int f = part * TB + threadIdx.x; f < kNQ; f += PARTS * TB) {
        const int rr = f / kQPR;           // row in [0, C*H)
        const int q  = f - rr * kQPR;
        const int j  = rr % kH;            // row within channel
        const bool rok = (j >= rlo) & (j < rhi);
        const float4 v4 = *(const float4*)(xb + rr * kW + q * 4);
        const float* v = (const float*)&v4;
        #pragma unroll
        for (int k = 0; k < 4; ++k) {
            const int i = q * 4 + k;
            const float val = (rok & (i >= clo) & (i < chi)) ? v[k] : 0.0f;
            vmin = fminf(vmin, val);
            vmax = fmaxf(vmax, val);
        }
    }

    // Wave (64-lane) shuffle reduction, then cross-wave via LDS.
    #pragma unroll
    for (int off = 32; off > 0; off >>= 1) {
        vmin = fminf(vmin, __shfl_down(vmin, off));
        vmax = fmaxf(vmax, __shfl_down(vmax, off));
    }
    __shared__ float smin[TB / 64], smax[TB / 64];
    const int wave = threadIdx.x >> 6, lane = threadIdx.x & 63;
    if (lane == 0) { smin[wave] = vmin; smax[wave] = vmax; }
    __syncthreads();
    if (threadIdx.x == 0) {
        float mn = smin[0], mx = smax[0];
        #pragma unroll
        for (int w2 = 1; w2 < TB / 64; ++w2) {
            mn = fminf(mn, smin[w2]);
            mx = fmaxf(mx, smax[w2]);
        }
        ws[img * PARTS + part] = make_float2(mn, mx);
    }
}

// ---------------- Kernel 2: gather + normalize + store ----------------
// Misaligned-by-sx gather as two aligned float4 loads + wave-uniform rotate
// (template on sx&3), clamped bases (clamped lanes always masked),
// per-element validity cndmask, aligned float4 store. (Verified in R2.)
template <int R>
__device__ __forceinline__ void gather_norm(const float* __restrict__ xb,
                                            float* __restrict__ ob,
                                            int sy, int sx, float mn, float inv,
                                            int f0)
{
    for (int f = f0; f < kNQ; f += PARTS * TB) {
        const int rr = f / kQPR;           // row in [0, C*H)
        const int q  = f - rr * kQPR;
        const int j  = rr % kH;            // row within channel
        const int c0 = rr - j;             // c * kH
        const int jj = j + sy;
        const bool rowok = (unsigned)jj < (unsigned)kH;
        const int jc = rowok ? jj : 0;     // clamp (masked anyway)
        const float* __restrict__ src = xb + (c0 + jc) * kW;

        const int i0 = q * 4;
        const int base = i0 + sx - R;      // multiple of 4 (R = sx & 3)
        int qa = base;       qa = qa < 0 ? 0 : qa; qa = qa > kW - 4 ? kW - 4 : qa;
        int qb = base + 4;   qb = qb < 0 ? 0 : qb; qb = qb > kW - 4 ? kW - 4 : qb;
        const float4 av = *(const float4*)(src + qa);
        const float4 bv = *(const float4*)(src + qb);
        const float* a = (const float*)&av;
        const float* b = (const float*)&bv;

        float sel[4];
        #pragma unroll
        for (int k = 0; k < 4; ++k)
            sel[k] = (k + R < 4) ? a[k + R] : b[k + R - 4];

        float4 o;
        float* po = (float*)&o;
        #pragma unroll
        for (int k = 0; k < 4; ++k) {
            const int s = i0 + k + sx;     // source column
            const float v = (rowok && (unsigned)s < (unsigned)kW) ? sel[k] : 0.0f;
            po[k] = (v - mn) * inv;
        }
        *(float4*)(ob + rr * kW + i0) = o; // 16B aligned
    }
}

__global__ __launch_bounds__(TB) void norm_k(
    const float* __restrict__ x, const float* __restrict__ sfy,
    const float* __restrict__ sfx, const float2* __restrict__ ws,
    float* __restrict__ out)
{
    const int img  = blockIdx.x / PARTS;
    const int part = blockIdx.x - img * PARTS;
    const float* __restrict__ xb = x + (size_t)img * kCHW;
    float* __restrict__ ob = out + (size_t)img * kCHW;

    int sy, sx; shifts_for(sfy, sfx, img, sy, sx);

    // Fold this image's 8 partials (uniform addresses -> scalar loads, L2-hit).
    float mn = INFINITY, mx = -INFINITY;
    #pragma unroll
    for (int p = 0; p < PARTS; ++p) {
        const float2 v = ws[img * PARTS + p];
        mn = fminf(mn, v.x);
        mx = fmaxf(mx, v.y);
    }
    const float inv = 1.0f / (mx - mn);

    const int f0 = part * TB + threadIdx.x;
    switch (sx & 3) {
        case 0: gather_norm<0>(xb, ob, sy, sx, mn, inv, f0); break;
        case 1: gather_norm<1>(xb, ob, sy, sx, mn, inv, f0); break;
        case 2: gather_norm<2>(xb, ob, sy, sx, mn, inv, f0); break;
        default: gather_norm<3>(xb, ob, sy, sx, mn, inv, f0); break;
    }
}

extern "C" void kernel_launch(void* const* d_in, const int* in_sizes, int n_in,
                              void* d_out, int out_size, void* d_ws, size_t ws_size,
                              hipStream_t stream) {
    const float* x  = (const float*)d_in[0];
    const float* fy = (const float*)d_in[1];
    const float* fx = (const float*)d_in[2];
    float* out = (float*)d_out;
    const int B = in_sizes[1];  // shift_fy has one element per image
    float2* ws = (float2*)d_ws; // B * PARTS float2 partials (16 KB @ B=256)
    minmax_k<<<B * PARTS, TB, 0, stream>>>(x, fy, fx, ws);
    norm_k<<<B * PARTS, TB, 0, stream>>>(x, fy, fx, ws, out);
}